// Round 13
// baseline (71.624 us; speedup 1.0000x reference)
//
#include <hip/hip_runtime.h>
#include <cstdint>
#include <cstddef>

#define SEQD 20
#define HID  512
#define LSEQ 2048
#define MROWS 8192
#define BM   32
#define GBK  64

typedef __attribute__((ext_vector_type(4))) float f32x4;
typedef __attribute__((ext_vector_type(8))) short bf16x8;

__device__ __forceinline__ ushort f2bf(float f) {
  union { float f; unsigned u; } v; v.f = f;
  unsigned r = v.u + 0x7fffu + ((v.u >> 16) & 1u);   // RNE
  return (ushort)(r >> 16);
}
// XOR-swizzle of byte offset b (0..127) within a 128B k-stripe, keyed by row.
// Involution on 16B-slot bits (4..6). Same XOR at ds_write and ds_read.
__device__ __forceinline__ int swzb(int row, int b) {
  return (b & 0x0F) | ((b ^ ((row & 7) << 4)) & 0x70);
}

// ===========================================================================
// Kernel 1: fully fused enc1 + gemm2 + heads, zero recompute.
// Each block owns rows bm..bm+31:
//   Phase A: h-tile A[32][512] = relu(X@W1+b1) computed ONCE -> swizzled bf16
//            LDS (resident for the whole kernel; no global round-trip).
//   Loop s=0..31 (xblk=s>>3, kt=s&7): stage B[128n][64k] from W2 (f32, L2-hot,
//            in-register 8kx4n transpose -> swizzled bf16 LDS, double-buffered)
//            + MFMA (wave tile 16x64, acc[4]).
//   Per xblk end: fold acc into per-row head partials pacc[4][7] (registers).
//   End: 16-lane shuffle reduce + wc-pair LDS combine -> write ssO/angO
//        directly, ci/cj to ws. No Hpart, no atomics, no zeroing.
// LDS: As 32KB + Bs 2x16KB + Xs 2.5KB + comb 2KB = 70KB -> 2 blocks/CU.
// ===========================================================================
__global__ __launch_bounds__(256, 2) void k_all(
    const float* __restrict__ X,   const float* __restrict__ W1,
    const float* __restrict__ b1,  const float* __restrict__ W2,
    const float* __restrict__ b2,  const float* __restrict__ Wss,
    const float* __restrict__ bss, const float* __restrict__ Wang,
    const float* __restrict__ bang,const float* __restrict__ Wc,
    float* __restrict__ ssO, float* __restrict__ angO,
    float* __restrict__ ci, float* __restrict__ cj) {
  __shared__ ushort As[BM * HID];          // 32 KB, [m][k] swizzled per stripe
  __shared__ ushort Bs[2][128 * GBK];      // 2 x 16 KB, [n][k] swizzled
  __shared__ float  Xs[SEQD][BM];          // 2.5 KB
  __shared__ float  comb[2][BM][8];        // 2 KB
  const int t = threadIdx.x;
  const int wave = t >> 6, lane = t & 63;
  const int l15 = lane & 15, lhi = lane >> 4;
  const int wr = wave >> 1, wc = wave & 1;
  const int bm = blockIdx.x * BM;

  // ---- Phase A: stage X, compute h-tile once into As ----
  for (int i = t; i < BM * SEQD; i += 256)
    Xs[i % SEQD][i / SEQD] = X[(size_t)bm * SEQD + i];
  __syncthreads();
  {
    const int r0  = (t >> 4) * 2;       // 2 rows per thread
    const int c0t = (t & 15) * 32;      // 32 cols per thread
    float aR[2][32];
#pragma unroll
    for (int c = 0; c < 32; ++c) {
      const float bv = b1[c0t + c];
      aR[0][c] = bv; aR[1][c] = bv;
    }
#pragma unroll
    for (int k = 0; k < SEQD; ++k) {
      const float x0 = Xs[k][r0], x1 = Xs[k][r0 + 1];
#pragma unroll
      for (int g = 0; g < 8; ++g) {
        const float4 w = *(const float4*)&W1[k * HID + c0t + g * 4];
        aR[0][g*4+0] += x0 * w.x; aR[0][g*4+1] += x0 * w.y;
        aR[0][g*4+2] += x0 * w.z; aR[0][g*4+3] += x0 * w.w;
        aR[1][g*4+0] += x1 * w.x; aR[1][g*4+1] += x1 * w.y;
        aR[1][g*4+2] += x1 * w.z; aR[1][g*4+3] += x1 * w.w;
      }
    }
#pragma unroll
    for (int r = 0; r < 2; ++r) {
      const int row = r0 + r;
#pragma unroll
      for (int g = 0; g < 4; ++g) {
        bf16x8 o;
#pragma unroll
        for (int e = 0; e < 8; ++e)
          o[e] = (short)f2bf(fmaxf(aR[r][g * 8 + e], 0.f));
        const int kbyte = (c0t + g * 8) * 2;   // byte offset within row
        *(bf16x8*)&As[(row * 1024 + (kbyte & ~127) + swzb(row, kbyte & 127)) >> 1] = o;
      }
    }
  }

  // B staging mapping (R12-proven): 8k x 4n per thread
  const int bnc = t & 31;                   // n within 32-group
  const int bkr = ((t & 63) >> 5) * 8 + wave * 16;  // k0 in 0..56 (4 waves x 2)

  f32x4 acc[4];
#pragma unroll
  for (int ni = 0; ni < 4; ++ni) acc[ni] = {0.f, 0.f, 0.f, 0.f};
  float pacc[4][7];
#pragma unroll
  for (int j = 0; j < 4; ++j)
#pragma unroll
    for (int q = 0; q < 7; ++q) pacc[j][q] = 0.f;

  float v[4][8];
#define BLOAD(kt_, xb_)                                                        \
  {                                                                            \
    const int c0 = (kt_) * GBK;                                                \
    const int bn = (xb_) * 128;                                                \
    _Pragma("unroll")                                                          \
    for (int i = 0; i < 8; ++i) {                                              \
      const float* wrp = &W2[(size_t)(c0 + bkr + i) * HID + bn + bnc];         \
      v[0][i] = wrp[0];  v[1][i] = wrp[32];                                    \
      v[2][i] = wrp[64]; v[3][i] = wrp[96];                                    \
    }                                                                          \
  }
#define BWRITE(buf_)                                                           \
  {                                                                            \
    _Pragma("unroll")                                                          \
    for (int q = 0; q < 4; ++q) {                                              \
      bf16x8 o;                                                                \
      _Pragma("unroll")                                                        \
      for (int i = 0; i < 8; ++i) o[i] = (short)f2bf(v[q][i]);                 \
      const int n = q * 32 + bnc;                                              \
      *(bf16x8*)&Bs[buf_][(n * 128 + swzb(n, bkr * 2)) >> 1] = o;              \
    }                                                                          \
  }
#define COMPUTE(buf_, kt_)                                                     \
  {                                                                            \
    _Pragma("unroll")                                                          \
    for (int kk = 0; kk < 2; ++kk) {                                           \
      const int arow = wr * 16 + l15;                                          \
      const bf16x8 af = *(const bf16x8*)&As[(arow * 1024 + (kt_) * 128 +       \
                                             swzb(arow, kk * 64 + lhi * 16)) >> 1]; \
      bf16x8 bff[4];                                                           \
      _Pragma("unroll")                                                        \
      for (int ni = 0; ni < 4; ++ni) {                                         \
        const int rn = wc * 64 + ni * 16 + l15;                                \
        bff[ni] = *(const bf16x8*)&Bs[buf_][(rn * 128 +                        \
                                             swzb(rn, kk * 64 + lhi * 16)) >> 1]; \
      }                                                                        \
      _Pragma("unroll")                                                        \
      for (int ni = 0; ni < 4; ++ni)                                           \
        acc[ni] = __builtin_amdgcn_mfma_f32_16x16x32_bf16(af, bff[ni], acc[ni], 0, 0, 0); \
    }                                                                          \
  }
#define HEADACC(xb_)                                                           \
  {                                                                            \
    _Pragma("unroll")                                                          \
    for (int ni = 0; ni < 4; ++ni) {                                           \
      const int col = (xb_) * 128 + wc * 64 + ni * 16 + l15;                   \
      const float bias = b2[col];                                              \
      const float s0w = Wss[col * 3 + 0], s1w = Wss[col * 3 + 1];              \
      const float s2w = Wss[col * 3 + 2];                                      \
      const float a0w = Wang[col * 2 + 0], a1w = Wang[col * 2 + 1];            \
      const float c0w = Wc[col], c1w = Wc[HID + col];                          \
      _Pragma("unroll")                                                        \
      for (int j = 0; j < 4; ++j) {                                            \
        const float hv = fmaxf(acc[ni][j] + bias, 0.f);                        \
        pacc[j][0] += hv * s0w; pacc[j][1] += hv * s1w; pacc[j][2] += hv * s2w;\
        pacc[j][3] += hv * a0w; pacc[j][4] += hv * a1w;                        \
        pacc[j][5] += hv * c0w; pacc[j][6] += hv * c1w;                        \
      }                                                                        \
      acc[ni] = (f32x4){0.f, 0.f, 0.f, 0.f};                                   \
    }                                                                          \
  }

  // prologue: stage step 0
  BLOAD(0, 0)
  BWRITE(0)
  __syncthreads();
  int cur = 0;
#pragma unroll 1
  for (int s = 0; s < 32; ++s) {
    const int kt = s & 7;
    if (s < 31) BLOAD((s + 1) & 7, (s + 1) >> 3)   // issue early (T14)
    COMPUTE(cur, kt)
    __syncthreads();                // reads of Bs[cur] done
    if (s < 31) BWRITE(cur ^ 1)     // write next tile (buf last read at s-1)
    __syncthreads();                // writes visible for step s+1
    cur ^= 1;
    if (kt == 7) HEADACC(s >> 3)    // fold this xblk's C into head partials
  }

  // ---- final: reduce pacc over 16 lanes, wc-pair combine, write heads ----
#pragma unroll
  for (int j = 0; j < 4; ++j)
#pragma unroll
    for (int q = 0; q < 7; ++q) {
      float p = pacc[j][q];
#pragma unroll
      for (int m = 1; m <= 8; m <<= 1) p += __shfl_xor(p, m);
      pacc[j][q] = p;
    }
  if (l15 == 0) {
#pragma unroll
    for (int j = 0; j < 4; ++j) {
      const int lr = wr * 16 + lhi * 4 + j;
#pragma unroll
      for (int q = 0; q < 7; ++q) comb[wc][lr][q] = pacc[j][q];
    }
  }
  __syncthreads();
  if (t < BM) {
    const int row = bm + t;
    float q[7];
#pragma unroll
    for (int qq = 0; qq < 7; ++qq) q[qq] = comb[0][t][qq] + comb[1][t][qq];
    const float l0 = q[0] + bss[0], l1 = q[1] + bss[1], l2 = q[2] + bss[2];
    const float mx = fmaxf(l0, fmaxf(l1, l2));
    const float e0 = __expf(l0 - mx), e1 = __expf(l1 - mx), e2 = __expf(l2 - mx);
    const float inv = 1.f / (e0 + e1 + e2);
    ssO[(size_t)row * 3 + 0] = e0 * inv;
    ssO[(size_t)row * 3 + 1] = e1 * inv;
    ssO[(size_t)row * 3 + 2] = e2 * inv;
    angO[(size_t)row * 2 + 0] = q[3] + bang[0];
    angO[(size_t)row * 2 + 1] = q[4] + bang[1];
    ci[row] = q[5];
    cj[row] = q[6];
  }
#undef BLOAD
#undef BWRITE
#undef COMPUTE
#undef HEADACC
}

// ===========================================================================
// Kernel 2: contact = sigmoid(ci + cj + bc). Pure 64MB write (floor ~10.5us).
// Grid 1024 = 4 batches x 256 tiles of 8 rows; cj batch-slice in LDS.
// ===========================================================================
__global__ __launch_bounds__(256) void k_fc(const float* __restrict__ ci,
                                            const float* __restrict__ cj,
                                            const float* __restrict__ bc,
                                            float* __restrict__ contact) {
  __shared__ float cj_l[LSEQ];
  __shared__ float ci_l[8];
  const int blk = blockIdx.x;
  const int b   = blk >> 8;
  const int i0  = (blk & 255) * 8;
  const int t   = threadIdx.x;
  const size_t rowbase = (size_t)b * LSEQ;

  {
    const float* cjb = cj + rowbase;
#pragma unroll
    for (int it = 0; it < 2; ++it) {
      const int j = it * 1024 + t * 4;
      *(float4*)&cj_l[j] = *(const float4*)&cjb[j];
    }
  }
  if (t < 8) ci_l[t] = ci[rowbase + i0 + t] + bc[0];
  __syncthreads();

#pragma unroll
  for (int r = 0; r < 8; ++r) {
    const float base = ci_l[r];
    float* orow = contact + (rowbase + i0 + r) * LSEQ;
#pragma unroll
    for (int jc = 0; jc < 2; ++jc) {
      const int j0 = jc * 1024 + t * 4;
      const float4 c4 = *(const float4*)&cj_l[j0];
      float4 o;
      o.x = 1.f / (1.f + __expf(-(base + c4.x)));
      o.y = 1.f / (1.f + __expf(-(base + c4.y)));
      o.z = 1.f / (1.f + __expf(-(base + c4.z)));
      o.w = 1.f / (1.f + __expf(-(base + c4.w)));
      *(float4*)&orow[j0] = o;
    }
  }
}

// ---------------------------------------------------------------------------
extern "C" void kernel_launch(void* const* d_in, const int* in_sizes, int n_in,
                              void* d_out, int out_size, void* d_ws, size_t ws_size,
                              hipStream_t stream) {
  const float* X    = (const float*)d_in[0];
  const float* W1   = (const float*)d_in[1];
  const float* b1   = (const float*)d_in[2];
  const float* W2   = (const float*)d_in[3];
  const float* b2   = (const float*)d_in[4];
  const float* Wss  = (const float*)d_in[5];
  const float* bss  = (const float*)d_in[6];
  const float* Wang = (const float*)d_in[7];
  const float* bang = (const float*)d_in[8];
  const float* Wc   = (const float*)d_in[9];
  const float* bc   = (const float*)d_in[10];

  float* out     = (float*)d_out;
  float* ssO     = out;                         // [8192,3]
  float* angO    = out + 24576;                 // [8192,2]
  float* contact = out + 40960;                 // [4,2048,2048]

  float* ci = (float*)d_ws;                     // 8192 floats
  float* cj = ci + MROWS;                       // 8192 floats

  k_all<<<256, 256, 0, stream>>>(X, W1, b1, W2, b2, Wss, bss, Wang, bang,
                                 Wc, ssO, angO, ci, cj);
  k_fc<<<1024, 256, 0, stream>>>(ci, cj, bc, contact);
}

// Round 14
// 44.079 us; speedup vs baseline: 1.6249x; 1.6249x over previous
//
#include <hip/hip_runtime.h>
#include <cstdint>
#include <cstddef>

#define SEQD 20
#define HID  512
#define LSEQ 2048
#define MROWS 8192
#define GBM 128
#define GBN 128
#define GBK 64
#define ITILE 8
#define ACC_FLOATS (6 * MROWS + MROWS)   // acc6[8192][6] + cjacc[8192]

typedef __attribute__((ext_vector_type(4))) float f32x4;
typedef __attribute__((ext_vector_type(8))) short bf16x8;

__device__ __forceinline__ ushort f2bf(float f) {
  union { float f; unsigned u; } v; v.f = f;
  unsigned r = v.u + 0x7fffu + ((v.u >> 16) & 1u);   // RNE
  return (ushort)(r >> 16);
}
// XOR-swizzle of byte offset b (0..127) within a 128B k-stripe, keyed by row.
// Involution on 16B-slot bits (4..6). Pre-swizzled at global write, same XOR
// at ds_read; LDS staging copies linearly (rule #21).
__device__ __forceinline__ int swzb(int row, int b) {
  return (b & 0x0F) | ((b ^ ((row & 7) << 4)) & 0x70);
}
__device__ __forceinline__ void async16(const ushort* g, ushort* l) {
  __builtin_amdgcn_global_load_lds(
      (const __attribute__((address_space(1))) unsigned*)g,
      (__attribute__((address_space(3))) unsigned*)l, 16, 0, 0);
}

// ---------------------------------------------------------------------------
// Kernel 1 (prep): blocks [0,512): h1 = relu(X@W1+b1) -> bf16, PRE-SWIZZLED.
//                  blocks [512,768): W2t transpose (PRE-SWIZZLED) + zero the
//                  head-accumulator region in ws (precedes gemm's atomics).
// ---------------------------------------------------------------------------
__global__ __launch_bounds__(256) void k_prep(const float* __restrict__ X,
                                              const float* __restrict__ W1,
                                              const float* __restrict__ b1,
                                              const float* __restrict__ W2,
                                              ushort* __restrict__ h1,
                                              ushort* __restrict__ W2t,
                                              float* __restrict__ accws) {
  __shared__ float Xs[16][SEQD + 1];
  __shared__ float tile[32][33];
  const int t = threadIdx.x;
  if (blockIdx.x < 512) {
    const int base = blockIdx.x * 16;
    for (int i = t; i < 16 * SEQD; i += 256) Xs[i / SEQD][i % SEQD] = X[base * SEQD + i];
    __syncthreads();
    const int m0 = (t >> 6) * 4;
    const int nl = (t & 63) * 4;
    float4 acc[4][2];
#pragma unroll
    for (int mi = 0; mi < 4; ++mi) {
      acc[mi][0] = *(const float4*)&b1[nl];
      acc[mi][1] = *(const float4*)&b1[nl + 256];
    }
#pragma unroll
    for (int k = 0; k < SEQD; ++k) {
      const float4 w0 = *(const float4*)&W1[k * HID + nl];
      const float4 w1 = *(const float4*)&W1[k * HID + nl + 256];
#pragma unroll
      for (int mi = 0; mi < 4; ++mi) {
        const float xv = Xs[m0 + mi][k];
        acc[mi][0].x += xv * w0.x; acc[mi][0].y += xv * w0.y;
        acc[mi][0].z += xv * w0.z; acc[mi][0].w += xv * w0.w;
        acc[mi][1].x += xv * w1.x; acc[mi][1].y += xv * w1.y;
        acc[mi][1].z += xv * w1.z; acc[mi][1].w += xv * w1.w;
      }
    }
#pragma unroll
    for (int mi = 0; mi < 4; ++mi) {
      const int m = base + m0 + mi;
#pragma unroll
      for (int g = 0; g < 2; ++g) {
        const float4 r = acc[mi][g];
        ushort4 o;
        o.x = f2bf(fmaxf(r.x, 0.f)); o.y = f2bf(fmaxf(r.y, 0.f));
        o.z = f2bf(fmaxf(r.z, 0.f)); o.w = f2bf(fmaxf(r.w, 0.f));
        const int k = nl + g * 256;
        const int sb = swzb(m, (k & 63) * 2);
        *(ushort4*)&h1[(size_t)m * HID + (k & ~63) + (sb >> 1)] = o;
      }
    }
  } else {
    const int zi = (blockIdx.x - 512) * 256 + t;
    if (zi < ACC_FLOATS) accws[zi] = 0.f;
    const int c = blockIdx.x - 512;
    const int k0 = (c & 15) * 32, n0 = (c >> 4) * 32;
    const int tx = t & 31, ty = t >> 5;
#pragma unroll
    for (int r = ty; r < 32; r += 8)
      tile[r][tx] = W2[(size_t)(k0 + r) * HID + n0 + tx];
    __syncthreads();
#pragma unroll
    for (int r = ty; r < 32; r += 8) {
      const int n = n0 + r, k = k0 + tx;
      const int sb = swzb(n, (k & 63) * 2);
      W2t[(size_t)n * HID + (k & ~63) + (sb >> 1)] = f2bf(tile[tx][r]);
    }
  }
}

// ---------------------------------------------------------------------------
// Kernel 2: gemm2 + fused heads. R7's exact geometry (BM=BN=128, grid 256,
// 4 waves 2x2) with the K-loop re-pipelined: 3 LDS buffers, 2-deep prefetch,
// counted s_waitcnt vmcnt(16) + raw s_barrier — steady state never drains
// vmcnt to 0 (T4; R7's __syncthreads drained freshly-issued loads 8x at
// 1 block/CU with zero TLP cover).
// WAR: STAGE(s+2) writes buf (s+2)%3 == (s-1)%3, last read before the
// end-of-step-(s-1) barrier. Visibility: per-wave vmcnt(16) covers stage s
// (8 loads/wave/stage; stages s+1,s+2 = 16 newer), then barrier aligns waves.
// ---------------------------------------------------------------------------
__global__ __launch_bounds__(256) void k_gemm_heads(const ushort* __restrict__ Aglob,
                                                    const ushort* __restrict__ Bglob,
                                                    const float* __restrict__ b2,
                                                    const float* __restrict__ Wss,
                                                    const float* __restrict__ Wang,
                                                    const float* __restrict__ Wc,
                                                    float* __restrict__ acc6,
                                                    float* __restrict__ cjacc) {
  __shared__ ushort As[3][GBM * GBK];      // 3 x 16 KB
  __shared__ ushort Bs[3][GBM * GBK];      // 3 x 16 KB
  __shared__ float  comb[2][GBM][8];       // 8 KB
  const int t = threadIdx.x;
  const int wave = t >> 6, lane = t & 63;
  const int l15 = lane & 15, lhi = lane >> 4;
  const int wr = wave >> 1, wc = wave & 1;
  const int swz = (blockIdx.x & 7) * 32 + (blockIdx.x >> 3);  // bijective, 256%8==0
  const int xblk = swz & 3, yblk = swz >> 2;
  const int bm = yblk * GBM, bn = xblk * GBN;
  const int srow = lane >> 3;
  const int scol = (lane & 7) * 8;

  f32x4 acc[4][4];
#pragma unroll
  for (int mi = 0; mi < 4; ++mi)
#pragma unroll
    for (int ni = 0; ni < 4; ++ni) acc[mi][ni] = {0.f, 0.f, 0.f, 0.f};

#define STAGE(buf, k0)                                                         \
  {                                                                            \
    _Pragma("unroll")                                                          \
    for (int rd = 0; rd < 4; ++rd) {                                           \
      const int r = rd * 32 + wave * 8 + srow;                                 \
      const int lo = rd * 2048 + wave * 512;                                   \
      async16(Aglob + (size_t)(bm + r) * HID + (k0) + scol, &As[buf][lo]);     \
      async16(Bglob + (size_t)(bn + r) * HID + (k0) + scol, &Bs[buf][lo]);     \
    }                                                                          \
  }

#define COMPUTE(buf)                                                           \
  {                                                                            \
    _Pragma("unroll")                                                          \
    for (int kk = 0; kk < 2; ++kk) {                                           \
      bf16x8 af[4], bff[4];                                                    \
      _Pragma("unroll")                                                        \
      for (int mi = 0; mi < 4; ++mi) {                                         \
        const int row = wr * 64 + mi * 16 + l15;                               \
        af[mi] = *(const bf16x8*)&As[buf][(row * 128 + swzb(row, kk * 64 + lhi * 16)) >> 1]; \
      }                                                                        \
      _Pragma("unroll")                                                        \
      for (int ni = 0; ni < 4; ++ni) {                                         \
        const int rn = wc * 64 + ni * 16 + l15;                                \
        bff[ni] = *(const bf16x8*)&Bs[buf][(rn * 128 + swzb(rn, kk * 64 + lhi * 16)) >> 1]; \
      }                                                                        \
      _Pragma("unroll")                                                        \
      for (int mi = 0; mi < 4; ++mi)                                           \
        _Pragma("unroll")                                                      \
        for (int ni = 0; ni < 4; ++ni)                                         \
          acc[mi][ni] = __builtin_amdgcn_mfma_f32_16x16x32_bf16(af[mi], bff[ni], acc[mi][ni], 0, 0, 0); \
    }                                                                          \
  }

// One pipeline step: prefetch stage s+2, wait only for stage s (counted),
// align waves, compute, then barrier to retire this buf's reads before it is
// overwritten two steps later.
#define STEP(s_, WAITS_)                                                       \
  {                                                                            \
    if ((s_) + 2 < 8) STAGE(((s_) + 2) % 3, ((s_) + 2) * GBK)                  \
    asm volatile("s_waitcnt vmcnt(" WAITS_ ")" ::: "memory");                  \
    __builtin_amdgcn_s_barrier();                                              \
    COMPUTE((s_) % 3);                                                         \
    __builtin_amdgcn_s_barrier();                                              \
  }

  // prologue: 2 stages in flight (16 loads/wave outstanding)
  STAGE(0, 0)
  STAGE(1, GBK)
  STEP(0, "16") STEP(1, "16") STEP(2, "16") STEP(3, "16")
  STEP(4, "16") STEP(5, "16") STEP(6, "8")  STEP(7, "0")

  // ---- epilogue (identical to R7): bias+relu, head partials, 16-lane
  //      reduce, wc-combine in LDS, per-row atomicAdd ----
  float bias[4], ws0[4], ws1[4], ws2[4], wa0[4], wa1[4], wc0[4], wc1[4];
#pragma unroll
  for (int ni = 0; ni < 4; ++ni) {
    const int col = bn + wc * 64 + ni * 16 + l15;
    bias[ni] = b2[col];
    ws0[ni] = Wss[col * 3 + 0]; ws1[ni] = Wss[col * 3 + 1]; ws2[ni] = Wss[col * 3 + 2];
    wa0[ni] = Wang[col * 2 + 0]; wa1[ni] = Wang[col * 2 + 1];
    wc0[ni] = Wc[col]; wc1[ni] = Wc[HID + col];
  }
#pragma unroll
  for (int mi = 0; mi < 4; ++mi) {
#pragma unroll
    for (int j = 0; j < 4; ++j) {
      float p0 = 0, p1 = 0, p2 = 0, p3 = 0, p4 = 0, p5 = 0, p6 = 0;
#pragma unroll
      for (int ni = 0; ni < 4; ++ni) {
        const float v = fmaxf(acc[mi][ni][j] + bias[ni], 0.f);
        p0 += v * ws0[ni]; p1 += v * ws1[ni]; p2 += v * ws2[ni];
        p3 += v * wa0[ni]; p4 += v * wa1[ni];
        p5 += v * wc0[ni]; p6 += v * wc1[ni];
      }
#pragma unroll
      for (int m = 1; m <= 8; m <<= 1) {
        p0 += __shfl_xor(p0, m); p1 += __shfl_xor(p1, m); p2 += __shfl_xor(p2, m);
        p3 += __shfl_xor(p3, m); p4 += __shfl_xor(p4, m);
        p5 += __shfl_xor(p5, m); p6 += __shfl_xor(p6, m);
      }
      if (l15 == 0) {
        const int lr = wr * 64 + mi * 16 + lhi * 4 + j;
        comb[wc][lr][0] = p0; comb[wc][lr][1] = p1; comb[wc][lr][2] = p2;
        comb[wc][lr][3] = p3; comb[wc][lr][4] = p4;
        comb[wc][lr][5] = p5; comb[wc][lr][6] = p6;
      }
    }
  }
  __syncthreads();
  if (t < GBM) {
    const int row = bm + t;
#pragma unroll
    for (int q = 0; q < 6; ++q)
      atomicAdd(&acc6[(size_t)row * 6 + q], comb[0][t][q] + comb[1][t][q]);
    atomicAdd(&cjacc[row], comb[0][t][6] + comb[1][t][6]);
  }
#undef STAGE
#undef COMPUTE
#undef STEP
}

// ---------------------------------------------------------------------------
// Kernel 3: finalize + contact (R7-identical). Grid 1024 = 4 batches x 256
// tiles of 8 rows; dense cjacc read -> LDS; 64KB sigmoid tile per block.
// ---------------------------------------------------------------------------
__global__ __launch_bounds__(256) void k_fc(const float* __restrict__ acc6,
                                            const float* __restrict__ cjacc,
                                            const float* __restrict__ bss,
                                            const float* __restrict__ bang,
                                            const float* __restrict__ bc,
                                            float* __restrict__ ssO,
                                            float* __restrict__ angO,
                                            float* __restrict__ contact) {
  __shared__ float cj_l[LSEQ];
  __shared__ float ci_l[ITILE];
  const int blk = blockIdx.x;
  const int b   = blk >> 8;
  const int i0  = (blk & 255) * ITILE;
  const int t   = threadIdx.x;
  const size_t rowbase = (size_t)b * LSEQ;

  {
    const float* cjb = cjacc + rowbase;
#pragma unroll
    for (int it = 0; it < 2; ++it) {
      const int j = it * 1024 + t * 4;
      *(float4*)&cj_l[j] = *(const float4*)&cjb[j];
    }
  }
  if (t < ITILE) {
    const size_t r = rowbase + i0 + t;
    const float* a = &acc6[r * 6];
    const float l0 = a[0] + bss[0], l1 = a[1] + bss[1], l2 = a[2] + bss[2];
    const float mx = fmaxf(l0, fmaxf(l1, l2));
    const float e0 = __expf(l0 - mx), e1 = __expf(l1 - mx), e2 = __expf(l2 - mx);
    const float inv = 1.f / (e0 + e1 + e2);
    ssO[r * 3 + 0] = e0 * inv;
    ssO[r * 3 + 1] = e1 * inv;
    ssO[r * 3 + 2] = e2 * inv;
    angO[r * 2 + 0] = a[3] + bang[0];
    angO[r * 2 + 1] = a[4] + bang[1];
    ci_l[t] = a[5] + bc[0];
  }
  __syncthreads();

#pragma unroll
  for (int r = 0; r < ITILE; ++r) {
    const float base = ci_l[r];
    float* orow = contact + (rowbase + i0 + r) * LSEQ;
#pragma unroll
    for (int jc = 0; jc < 2; ++jc) {
      const int j0 = jc * 1024 + t * 4;
      const float4 c4 = *(const float4*)&cj_l[j0];
      float4 o;
      o.x = 1.f / (1.f + __expf(-(base + c4.x)));
      o.y = 1.f / (1.f + __expf(-(base + c4.y)));
      o.z = 1.f / (1.f + __expf(-(base + c4.z)));
      o.w = 1.f / (1.f + __expf(-(base + c4.w)));
      *(float4*)&orow[j0] = o;
    }
  }
}

// ---------------------------------------------------------------------------
extern "C" void kernel_launch(void* const* d_in, const int* in_sizes, int n_in,
                              void* d_out, int out_size, void* d_ws, size_t ws_size,
                              hipStream_t stream) {
  const float* X    = (const float*)d_in[0];
  const float* W1   = (const float*)d_in[1];
  const float* b1   = (const float*)d_in[2];
  const float* W2   = (const float*)d_in[3];
  const float* b2   = (const float*)d_in[4];
  const float* Wss  = (const float*)d_in[5];
  const float* bss  = (const float*)d_in[6];
  const float* Wang = (const float*)d_in[7];
  const float* bang = (const float*)d_in[8];
  const float* Wc   = (const float*)d_in[9];
  const float* bc   = (const float*)d_in[10];

  float* out     = (float*)d_out;
  float* ssO     = out;                         // [8192,3]
  float* angO    = out + 24576;                 // [8192,2]
  float* contact = out + 40960;                 // [4,2048,2048]

  // h1/W2t scratch inside the not-yet-written contact region (k_fc reads
  // only ws + biases and overwrites the region last).
  ushort* h1  = (ushort*)contact;                        // 8 MB  (swizzled)
  ushort* W2t = (ushort*)(contact + 2 * 1024 * 1024);    // 512 KB (swizzled)

  // ws layout: acc6[8192][6] | cjacc[8192]
  float* acc6  = (float*)d_ws;
  float* cjacc = acc6 + (size_t)6 * MROWS;

  k_prep<<<768, 256, 0, stream>>>(X, W1, b1, W2, h1, W2t, acc6);
  k_gemm_heads<<<256, 256, 0, stream>>>(h1, W2t, b2, Wss, Wang, Wc, acc6, cjacc);
  k_fc<<<1024, 256, 0, stream>>>(acc6, cjacc, bss, bang, bc, ssO, angO, contact);
}

// Round 15
// 42.272 us; speedup vs baseline: 1.6944x; 1.0428x over previous
//
#include <hip/hip_runtime.h>
#include <cstdint>
#include <cstddef>

#define SEQD 20
#define HID  512
#define LSEQ 2048
#define MROWS 8192
#define BM   64
#define BN   128
#define GBK  64
#define ITILE 8
#define ACC_FLOATS (6 * MROWS + MROWS)   // acc6[8192][6] + cjacc[8192]

typedef __attribute__((ext_vector_type(4))) float f32x4;
typedef __attribute__((ext_vector_type(8))) short bf16x8;

__device__ __forceinline__ ushort f2bf(float f) {
  union { float f; unsigned u; } v; v.f = f;
  unsigned r = v.u + 0x7fffu + ((v.u >> 16) & 1u);   // RNE
  return (ushort)(r >> 16);
}
// XOR-swizzle of byte offset b (0..127) within a 128B k-stripe, keyed by row.
// Involution on 16B-slot bits (4..6). Pre-swizzled at global write, same XOR
// at ds_read; LDS staging copies linearly (rule #21).
__device__ __forceinline__ int swzb(int row, int b) {
  return (b & 0x0F) | ((b ^ ((row & 7) << 4)) & 0x70);
}
__device__ __forceinline__ void async16(const ushort* g, ushort* l) {
  __builtin_amdgcn_global_load_lds(
      (const __attribute__((address_space(1))) unsigned*)g,
      (__attribute__((address_space(3))) unsigned*)l, 16, 0, 0);
}

// ---------------------------------------------------------------------------
// Kernel 1 (prep): UNCHANGED from R14. blocks [0,512): h1 pre-swizzled bf16;
// blocks [512,768): W2t transpose pre-swizzled + zero head accumulators.
// ---------------------------------------------------------------------------
__global__ __launch_bounds__(256) void k_prep(const float* __restrict__ X,
                                              const float* __restrict__ W1,
                                              const float* __restrict__ b1,
                                              const float* __restrict__ W2,
                                              ushort* __restrict__ h1,
                                              ushort* __restrict__ W2t,
                                              float* __restrict__ accws) {
  __shared__ float Xs[16][SEQD + 1];
  __shared__ float tile[32][33];
  const int t = threadIdx.x;
  if (blockIdx.x < 512) {
    const int base = blockIdx.x * 16;
    for (int i = t; i < 16 * SEQD; i += 256) Xs[i / SEQD][i % SEQD] = X[base * SEQD + i];
    __syncthreads();
    const int m0 = (t >> 6) * 4;
    const int nl = (t & 63) * 4;
    float4 acc[4][2];
#pragma unroll
    for (int mi = 0; mi < 4; ++mi) {
      acc[mi][0] = *(const float4*)&b1[nl];
      acc[mi][1] = *(const float4*)&b1[nl + 256];
    }
#pragma unroll
    for (int k = 0; k < SEQD; ++k) {
      const float4 w0 = *(const float4*)&W1[k * HID + nl];
      const float4 w1 = *(const float4*)&W1[k * HID + nl + 256];
#pragma unroll
      for (int mi = 0; mi < 4; ++mi) {
        const float xv = Xs[m0 + mi][k];
        acc[mi][0].x += xv * w0.x; acc[mi][0].y += xv * w0.y;
        acc[mi][0].z += xv * w0.z; acc[mi][0].w += xv * w0.w;
        acc[mi][1].x += xv * w1.x; acc[mi][1].y += xv * w1.y;
        acc[mi][1].z += xv * w1.z; acc[mi][1].w += xv * w1.w;
      }
    }
#pragma unroll
    for (int mi = 0; mi < 4; ++mi) {
      const int m = base + m0 + mi;
#pragma unroll
      for (int g = 0; g < 2; ++g) {
        const float4 r = acc[mi][g];
        ushort4 o;
        o.x = f2bf(fmaxf(r.x, 0.f)); o.y = f2bf(fmaxf(r.y, 0.f));
        o.z = f2bf(fmaxf(r.z, 0.f)); o.w = f2bf(fmaxf(r.w, 0.f));
        const int k = nl + g * 256;
        const int sb = swzb(m, (k & 63) * 2);
        *(ushort4*)&h1[(size_t)m * HID + (k & ~63) + (sb >> 1)] = o;
      }
    }
  } else {
    const int zi = (blockIdx.x - 512) * 256 + t;
    if (zi < ACC_FLOATS) accws[zi] = 0.f;
    const int c = blockIdx.x - 512;
    const int k0 = (c & 15) * 32, n0 = (c >> 4) * 32;
    const int tx = t & 31, ty = t >> 5;
#pragma unroll
    for (int r = ty; r < 32; r += 8)
      tile[r][tx] = W2[(size_t)(k0 + r) * HID + n0 + tx];
    __syncthreads();
#pragma unroll
    for (int r = ty; r < 32; r += 8) {
      const int n = n0 + r, k = k0 + tx;
      const int sb = swzb(n, (k & 63) * 2);
      W2t[(size_t)n * HID + (k & ~63) + (sb >> 1)] = f2bf(tile[tx][r]);
    }
  }
}

// ---------------------------------------------------------------------------
// Kernel 2: gemm2 + fused heads. R14's counted-vmcnt 3-buffer 2-deep schedule
// UNCHANGED; geometry BM=64 x BN=128, grid 512 = 2 blocks/CU (the R14 grid of
// 256 pinned occupancy to 1 block/CU — every barrier stalled the whole CU).
// LDS 76KB -> 2 resident blocks; B re-reads are per-XCD-L2-resident (512KB).
// Per-wave stage = 6 loads (A:2 + B:4) -> steady vmcnt(12), tail 6/0.
// ---------------------------------------------------------------------------
__global__ __launch_bounds__(256, 2) void k_gemm_heads(const ushort* __restrict__ Aglob,
                                                       const ushort* __restrict__ Bglob,
                                                       const float* __restrict__ b2,
                                                       const float* __restrict__ Wss,
                                                       const float* __restrict__ Wang,
                                                       const float* __restrict__ Wc,
                                                       float* __restrict__ acc6,
                                                       float* __restrict__ cjacc) {
  __shared__ ushort As[3][BM * GBK];       // 3 x 8 KB
  __shared__ ushort Bs[3][BN * GBK];       // 3 x 16 KB
  __shared__ float  comb[2][BM][8];        // 4 KB
  const int t = threadIdx.x;
  const int wave = t >> 6, lane = t & 63;
  const int l15 = lane & 15, lhi = lane >> 4;
  const int wr = wave >> 1, wc = wave & 1;
  const int swz = (blockIdx.x & 7) * 64 + (blockIdx.x >> 3);  // bijective, 512%8==0
  const int xblk = swz & 3, yblk = swz >> 2;
  const int bm = yblk * BM, bn = xblk * BN;
  const int srow = lane >> 3;
  const int scol = (lane & 7) * 8;

  f32x4 acc[2][4];
#pragma unroll
  for (int mi = 0; mi < 2; ++mi)
#pragma unroll
    for (int ni = 0; ni < 4; ++ni) acc[mi][ni] = {0.f, 0.f, 0.f, 0.f};

#define STAGE(buf, k0)                                                         \
  {                                                                            \
    _Pragma("unroll")                                                          \
    for (int rd = 0; rd < 2; ++rd) {                                           \
      const int r = rd * 32 + wave * 8 + srow;                                 \
      async16(Aglob + (size_t)(bm + r) * HID + (k0) + scol,                    \
              &As[buf][rd * 2048 + wave * 512]);                               \
    }                                                                          \
    _Pragma("unroll")                                                          \
    for (int rd = 0; rd < 4; ++rd) {                                           \
      const int r = rd * 32 + wave * 8 + srow;                                 \
      async16(Bglob + (size_t)(bn + r) * HID + (k0) + scol,                    \
              &Bs[buf][rd * 2048 + wave * 512]);                               \
    }                                                                          \
  }

#define COMPUTE(buf)                                                           \
  {                                                                            \
    _Pragma("unroll")                                                          \
    for (int kk = 0; kk < 2; ++kk) {                                           \
      bf16x8 af[2], bff[4];                                                    \
      _Pragma("unroll")                                                        \
      for (int mi = 0; mi < 2; ++mi) {                                         \
        const int row = wr * 32 + mi * 16 + l15;                               \
        af[mi] = *(const bf16x8*)&As[buf][(row * 128 + swzb(row, kk * 64 + lhi * 16)) >> 1]; \
      }                                                                        \
      _Pragma("unroll")                                                        \
      for (int ni = 0; ni < 4; ++ni) {                                         \
        const int rn = wc * 64 + ni * 16 + l15;                                \
        bff[ni] = *(const bf16x8*)&Bs[buf][(rn * 128 + swzb(rn, kk * 64 + lhi * 16)) >> 1]; \
      }                                                                        \
      _Pragma("unroll")                                                        \
      for (int mi = 0; mi < 2; ++mi)                                           \
        _Pragma("unroll")                                                      \
        for (int ni = 0; ni < 4; ++ni)                                         \
          acc[mi][ni] = __builtin_amdgcn_mfma_f32_16x16x32_bf16(af[mi], bff[ni], acc[mi][ni], 0, 0, 0); \
    }                                                                          \
  }

// Pipeline step (R14 semantics): prefetch stage s+2, counted wait for stage s,
// align waves, compute, barrier before this buf is overwritten 2 steps later.
#define STEP(s_, WAITS_)                                                       \
  {                                                                            \
    if ((s_) + 2 < 8) STAGE(((s_) + 2) % 3, ((s_) + 2) * GBK)                  \
    asm volatile("s_waitcnt vmcnt(" WAITS_ ")" ::: "memory");                  \
    __builtin_amdgcn_s_barrier();                                              \
    COMPUTE((s_) % 3);                                                         \
    __builtin_amdgcn_s_barrier();                                              \
  }

  STAGE(0, 0)
  STAGE(1, GBK)
  STEP(0, "12") STEP(1, "12") STEP(2, "12") STEP(3, "12")
  STEP(4, "12") STEP(5, "12") STEP(6, "6")  STEP(7, "0")

  // ---- epilogue: bias+relu, head partials, 16-lane reduce, wc-combine,
  //      per-row atomicAdd (4 adds/row: one per xblk) ----
  float bias[4], ws0[4], ws1[4], ws2[4], wa0[4], wa1[4], wc0[4], wc1[4];
#pragma unroll
  for (int ni = 0; ni < 4; ++ni) {
    const int col = bn + wc * 64 + ni * 16 + l15;
    bias[ni] = b2[col];
    ws0[ni] = Wss[col * 3 + 0]; ws1[ni] = Wss[col * 3 + 1]; ws2[ni] = Wss[col * 3 + 2];
    wa0[ni] = Wang[col * 2 + 0]; wa1[ni] = Wang[col * 2 + 1];
    wc0[ni] = Wc[col]; wc1[ni] = Wc[HID + col];
  }
#pragma unroll
  for (int mi = 0; mi < 2; ++mi) {
#pragma unroll
    for (int j = 0; j < 4; ++j) {
      float p0 = 0, p1 = 0, p2 = 0, p3 = 0, p4 = 0, p5 = 0, p6 = 0;
#pragma unroll
      for (int ni = 0; ni < 4; ++ni) {
        const float v = fmaxf(acc[mi][ni][j] + bias[ni], 0.f);
        p0 += v * ws0[ni]; p1 += v * ws1[ni]; p2 += v * ws2[ni];
        p3 += v * wa0[ni]; p4 += v * wa1[ni];
        p5 += v * wc0[ni]; p6 += v * wc1[ni];
      }
#pragma unroll
      for (int m = 1; m <= 8; m <<= 1) {
        p0 += __shfl_xor(p0, m); p1 += __shfl_xor(p1, m); p2 += __shfl_xor(p2, m);
        p3 += __shfl_xor(p3, m); p4 += __shfl_xor(p4, m);
        p5 += __shfl_xor(p5, m); p6 += __shfl_xor(p6, m);
      }
      if (l15 == 0) {
        const int lr = wr * 32 + mi * 16 + lhi * 4 + j;   // local row 0..63
        comb[wc][lr][0] = p0; comb[wc][lr][1] = p1; comb[wc][lr][2] = p2;
        comb[wc][lr][3] = p3; comb[wc][lr][4] = p4;
        comb[wc][lr][5] = p5; comb[wc][lr][6] = p6;
      }
    }
  }
  __syncthreads();
  if (t < BM) {
    const int row = bm + t;
#pragma unroll
    for (int q = 0; q < 6; ++q)
      atomicAdd(&acc6[(size_t)row * 6 + q], comb[0][t][q] + comb[1][t][q]);
    atomicAdd(&cjacc[row], comb[0][t][6] + comb[1][t][6]);
  }
#undef STAGE
#undef COMPUTE
#undef STEP
}

// ---------------------------------------------------------------------------
// Kernel 3: finalize + contact (UNCHANGED from R14).
// ---------------------------------------------------------------------------
__global__ __launch_bounds__(256) void k_fc(const float* __restrict__ acc6,
                                            const float* __restrict__ cjacc,
                                            const float* __restrict__ bss,
                                            const float* __restrict__ bang,
                                            const float* __restrict__ bc,
                                            float* __restrict__ ssO,
                                            float* __restrict__ angO,
                                            float* __restrict__ contact) {
  __shared__ float cj_l[LSEQ];
  __shared__ float ci_l[ITILE];
  const int blk = blockIdx.x;
  const int b   = blk >> 8;
  const int i0  = (blk & 255) * ITILE;
  const int t   = threadIdx.x;
  const size_t rowbase = (size_t)b * LSEQ;

  {
    const float* cjb = cjacc + rowbase;
#pragma unroll
    for (int it = 0; it < 2; ++it) {
      const int j = it * 1024 + t * 4;
      *(float4*)&cj_l[j] = *(const float4*)&cjb[j];
    }
  }
  if (t < ITILE) {
    const size_t r = rowbase + i0 + t;
    const float* a = &acc6[r * 6];
    const float l0 = a[0] + bss[0], l1 = a[1] + bss[1], l2 = a[2] + bss[2];
    const float mx = fmaxf(l0, fmaxf(l1, l2));
    const float e0 = __expf(l0 - mx), e1 = __expf(l1 - mx), e2 = __expf(l2 - mx);
    const float inv = 1.f / (e0 + e1 + e2);
    ssO[r * 3 + 0] = e0 * inv;
    ssO[r * 3 + 1] = e1 * inv;
    ssO[r * 3 + 2] = e2 * inv;
    angO[r * 2 + 0] = a[3] + bang[0];
    angO[r * 2 + 1] = a[4] + bang[1];
    ci_l[t] = a[5] + bc[0];
  }
  __syncthreads();

#pragma unroll
  for (int r = 0; r < ITILE; ++r) {
    const float base = ci_l[r];
    float* orow = contact + (rowbase + i0 + r) * LSEQ;
#pragma unroll
    for (int jc = 0; jc < 2; ++jc) {
      const int j0 = jc * 1024 + t * 4;
      const float4 c4 = *(const float4*)&cj_l[j0];
      float4 o;
      o.x = 1.f / (1.f + __expf(-(base + c4.x)));
      o.y = 1.f / (1.f + __expf(-(base + c4.y)));
      o.z = 1.f / (1.f + __expf(-(base + c4.z)));
      o.w = 1.f / (1.f + __expf(-(base + c4.w)));
      *(float4*)&orow[j0] = o;
    }
  }
}

// ---------------------------------------------------------------------------
extern "C" void kernel_launch(void* const* d_in, const int* in_sizes, int n_in,
                              void* d_out, int out_size, void* d_ws, size_t ws_size,
                              hipStream_t stream) {
  const float* X    = (const float*)d_in[0];
  const float* W1   = (const float*)d_in[1];
  const float* b1   = (const float*)d_in[2];
  const float* W2   = (const float*)d_in[3];
  const float* b2   = (const float*)d_in[4];
  const float* Wss  = (const float*)d_in[5];
  const float* bss  = (const float*)d_in[6];
  const float* Wang = (const float*)d_in[7];
  const float* bang = (const float*)d_in[8];
  const float* Wc   = (const float*)d_in[9];
  const float* bc   = (const float*)d_in[10];

  float* out     = (float*)d_out;
  float* ssO     = out;                         // [8192,3]
  float* angO    = out + 24576;                 // [8192,2]
  float* contact = out + 40960;                 // [4,2048,2048]

  // h1/W2t scratch inside the not-yet-written contact region (k_fc reads
  // only ws + biases and overwrites the region last).
  ushort* h1  = (ushort*)contact;                        // 8 MB  (swizzled)
  ushort* W2t = (ushort*)(contact + 2 * 1024 * 1024);    // 512 KB (swizzled)

  // ws layout: acc6[8192][6] | cjacc[8192]
  float* acc6  = (float*)d_ws;
  float* cjacc = acc6 + (size_t)6 * MROWS;

  k_prep<<<768, 256, 0, stream>>>(X, W1, b1, W2, h1, W2t, acc6);
  k_gemm_heads<<<512, 256, 0, stream>>>(h1, W2t, b2, Wss, Wang, Wc, acc6, cjacc);
  k_fc<<<1024, 256, 0, stream>>>(acc6, cjacc, bss, bang, bc, ssO, angO, contact);
}

// Round 17
// 39.843 us; speedup vs baseline: 1.7976x; 1.0609x over previous
//
#include <hip/hip_runtime.h>
#include <cstdint>
#include <cstddef>

#define SEQD 20
#define HID  512
#define LSEQ 2048
#define MROWS 8192
#define BM   64
#define BN   128
#define GBK  64
#define ITILE 8

typedef __attribute__((ext_vector_type(4))) float f32x4;
typedef __attribute__((ext_vector_type(8))) short bf16x8;

__device__ __forceinline__ ushort f2bf(float f) {
  union { float f; unsigned u; } v; v.f = f;
  unsigned r = v.u + 0x7fffu + ((v.u >> 16) & 1u);   // RNE
  return (ushort)(r >> 16);
}
// XOR-swizzle of byte offset b (0..127) within a 128B k-stripe, keyed by row.
// Involution on 16B-slot bits (4..6). Pre-swizzled at global write, same XOR
// at ds_read; LDS staging copies linearly (rule #21).
__device__ __forceinline__ int swzb(int row, int b) {
  return (b & 0x0F) | ((b ^ ((row & 7) << 4)) & 0x70);
}
__device__ __forceinline__ void async16(const ushort* g, ushort* l) {
  __builtin_amdgcn_global_load_lds(
      (const __attribute__((address_space(1))) unsigned*)g,
      (__attribute__((address_space(3))) unsigned*)l, 16, 0, 0);
}

// ---------------------------------------------------------------------------
// Kernel 1 (prep): blocks [0,512): h1 = relu(X@W1+b1) -> bf16 PRE-SWIZZLED;
// blocks [512,768): W2t transpose pre-swizzled. (Zeroing removed — the gemm
// epilogue now writes Hpart planes deterministically, no atomics.)
// ---------------------------------------------------------------------------
__global__ __launch_bounds__(256) void k_prep(const float* __restrict__ X,
                                              const float* __restrict__ W1,
                                              const float* __restrict__ b1,
                                              const float* __restrict__ W2,
                                              ushort* __restrict__ h1,
                                              ushort* __restrict__ W2t) {
  __shared__ float Xs[16][SEQD + 1];
  __shared__ float tile[32][33];
  const int t = threadIdx.x;
  if (blockIdx.x < 512) {
    const int base = blockIdx.x * 16;
    for (int i = t; i < 16 * SEQD; i += 256) Xs[i / SEQD][i % SEQD] = X[base * SEQD + i];
    __syncthreads();
    const int m0 = (t >> 6) * 4;
    const int nl = (t & 63) * 4;
    float4 acc[4][2];
#pragma unroll
    for (int mi = 0; mi < 4; ++mi) {
      acc[mi][0] = *(const float4*)&b1[nl];
      acc[mi][1] = *(const float4*)&b1[nl + 256];
    }
#pragma unroll
    for (int k = 0; k < SEQD; ++k) {
      const float4 w0 = *(const float4*)&W1[k * HID + nl];
      const float4 w1 = *(const float4*)&W1[k * HID + nl + 256];
#pragma unroll
      for (int mi = 0; mi < 4; ++mi) {
        const float xv = Xs[m0 + mi][k];
        acc[mi][0].x += xv * w0.x; acc[mi][0].y += xv * w0.y;
        acc[mi][0].z += xv * w0.z; acc[mi][0].w += xv * w0.w;
        acc[mi][1].x += xv * w1.x; acc[mi][1].y += xv * w1.y;
        acc[mi][1].z += xv * w1.z; acc[mi][1].w += xv * w1.w;
      }
    }
#pragma unroll
    for (int mi = 0; mi < 4; ++mi) {
      const int m = base + m0 + mi;
#pragma unroll
      for (int g = 0; g < 2; ++g) {
        const float4 r = acc[mi][g];
        ushort4 o;
        o.x = f2bf(fmaxf(r.x, 0.f)); o.y = f2bf(fmaxf(r.y, 0.f));
        o.z = f2bf(fmaxf(r.z, 0.f)); o.w = f2bf(fmaxf(r.w, 0.f));
        const int k = nl + g * 256;
        const int sb = swzb(m, (k & 63) * 2);
        *(ushort4*)&h1[(size_t)m * HID + (k & ~63) + (sb >> 1)] = o;
      }
    }
  } else {
    const int c = blockIdx.x - 512;
    const int k0 = (c & 15) * 32, n0 = (c >> 4) * 32;
    const int tx = t & 31, ty = t >> 5;
#pragma unroll
    for (int r = ty; r < 32; r += 8)
      tile[r][tx] = W2[(size_t)(k0 + r) * HID + n0 + tx];
    __syncthreads();
#pragma unroll
    for (int r = ty; r < 32; r += 8) {
      const int n = n0 + r, k = k0 + tx;
      const int sb = swzb(n, (k & 63) * 2);
      W2t[(size_t)n * HID + (k & ~63) + (sb >> 1)] = f2bf(tile[tx][r]);
    }
  }
}

// ---------------------------------------------------------------------------
// Kernel 2: gemm2 + fused heads. R15's geometry + counted-vmcnt schedule
// UNCHANGED (BM=64 x BN=128, grid 512 = 2 blocks/CU, 3-buffer 2-deep
// prefetch, vmcnt(12) steady). Epilogue changed: deterministic plane writes
// Hpart[xblk][q][row] instead of 229K contended atomicAdds.
// ---------------------------------------------------------------------------
__global__ __launch_bounds__(256, 2) void k_gemm_heads(const ushort* __restrict__ Aglob,
                                                       const ushort* __restrict__ Bglob,
                                                       const float* __restrict__ b2,
                                                       const float* __restrict__ Wss,
                                                       const float* __restrict__ Wang,
                                                       const float* __restrict__ Wc,
                                                       float* __restrict__ Hpart) {
  __shared__ ushort As[3][BM * GBK];       // 3 x 8 KB
  __shared__ ushort Bs[3][BN * GBK];       // 3 x 16 KB
  __shared__ float  comb[2][BM][8];        // 4 KB
  const int t = threadIdx.x;
  const int wave = t >> 6, lane = t & 63;
  const int l15 = lane & 15, lhi = lane >> 4;
  const int wr = wave >> 1, wc = wave & 1;
  const int swz = (blockIdx.x & 7) * 64 + (blockIdx.x >> 3);  // bijective, 512%8==0
  const int xblk = swz & 3, yblk = swz >> 2;
  const int bm = yblk * BM, bn = xblk * BN;
  const int srow = lane >> 3;
  const int scol = (lane & 7) * 8;

  f32x4 acc[2][4];
#pragma unroll
  for (int mi = 0; mi < 2; ++mi)
#pragma unroll
    for (int ni = 0; ni < 4; ++ni) acc[mi][ni] = {0.f, 0.f, 0.f, 0.f};

#define STAGE(buf, k0)                                                         \
  {                                                                            \
    _Pragma("unroll")                                                          \
    for (int rd = 0; rd < 2; ++rd) {                                           \
      const int r = rd * 32 + wave * 8 + srow;                                 \
      async16(Aglob + (size_t)(bm + r) * HID + (k0) + scol,                    \
              &As[buf][rd * 2048 + wave * 512]);                               \
    }                                                                          \
    _Pragma("unroll")                                                          \
    for (int rd = 0; rd < 4; ++rd) {                                           \
      const int r = rd * 32 + wave * 8 + srow;                                 \
      async16(Bglob + (size_t)(bn + r) * HID + (k0) + scol,                    \
              &Bs[buf][rd * 2048 + wave * 512]);                               \
    }                                                                          \
  }

#define COMPUTE(buf)                                                           \
  {                                                                            \
    _Pragma("unroll")                                                          \
    for (int kk = 0; kk < 2; ++kk) {                                           \
      bf16x8 af[2], bff[4];                                                    \
      _Pragma("unroll")                                                        \
      for (int mi = 0; mi < 2; ++mi) {                                         \
        const int row = wr * 32 + mi * 16 + l15;                               \
        af[mi] = *(const bf16x8*)&As[buf][(row * 128 + swzb(row, kk * 64 + lhi * 16)) >> 1]; \
      }                                                                        \
      _Pragma("unroll")                                                        \
      for (int ni = 0; ni < 4; ++ni) {                                         \
        const int rn = wc * 64 + ni * 16 + l15;                                \
        bff[ni] = *(const bf16x8*)&Bs[buf][(rn * 128 + swzb(rn, kk * 64 + lhi * 16)) >> 1]; \
      }                                                                        \
      _Pragma("unroll")                                                        \
      for (int mi = 0; mi < 2; ++mi)                                           \
        _Pragma("unroll")                                                      \
        for (int ni = 0; ni < 4; ++ni)                                         \
          acc[mi][ni] = __builtin_amdgcn_mfma_f32_16x16x32_bf16(af[mi], bff[ni], acc[mi][ni], 0, 0, 0); \
    }                                                                          \
  }

#define STEP(s_, WAITS_)                                                       \
  {                                                                            \
    if ((s_) + 2 < 8) STAGE(((s_) + 2) % 3, ((s_) + 2) * GBK)                  \
    asm volatile("s_waitcnt vmcnt(" WAITS_ ")" ::: "memory");                  \
    __builtin_amdgcn_s_barrier();                                              \
    COMPUTE((s_) % 3);                                                         \
    __builtin_amdgcn_s_barrier();                                              \
  }

  STAGE(0, 0)
  STAGE(1, GBK)
  STEP(0, "12") STEP(1, "12") STEP(2, "12") STEP(3, "12")
  STEP(4, "12") STEP(5, "12") STEP(6, "6")  STEP(7, "0")

  // ---- epilogue: bias+relu, head partials, 16-lane reduce, wc-combine,
  //      deterministic coalesced plane writes (no atomics) ----
  float bias[4], ws0[4], ws1[4], ws2[4], wa0[4], wa1[4], wc0[4], wc1[4];
#pragma unroll
  for (int ni = 0; ni < 4; ++ni) {
    const int col = bn + wc * 64 + ni * 16 + l15;
    bias[ni] = b2[col];
    ws0[ni] = Wss[col * 3 + 0]; ws1[ni] = Wss[col * 3 + 1]; ws2[ni] = Wss[col * 3 + 2];
    wa0[ni] = Wang[col * 2 + 0]; wa1[ni] = Wang[col * 2 + 1];
    wc0[ni] = Wc[col]; wc1[ni] = Wc[HID + col];
  }
#pragma unroll
  for (int mi = 0; mi < 2; ++mi) {
#pragma unroll
    for (int j = 0; j < 4; ++j) {
      float p0 = 0, p1 = 0, p2 = 0, p3 = 0, p4 = 0, p5 = 0, p6 = 0;
#pragma unroll
      for (int ni = 0; ni < 4; ++ni) {
        const float v = fmaxf(acc[mi][ni][j] + bias[ni], 0.f);
        p0 += v * ws0[ni]; p1 += v * ws1[ni]; p2 += v * ws2[ni];
        p3 += v * wa0[ni]; p4 += v * wa1[ni];
        p5 += v * wc0[ni]; p6 += v * wc1[ni];
      }
#pragma unroll
      for (int m = 1; m <= 8; m <<= 1) {
        p0 += __shfl_xor(p0, m); p1 += __shfl_xor(p1, m); p2 += __shfl_xor(p2, m);
        p3 += __shfl_xor(p3, m); p4 += __shfl_xor(p4, m);
        p5 += __shfl_xor(p5, m); p6 += __shfl_xor(p6, m);
      }
      if (l15 == 0) {
        const int lr = wr * 32 + mi * 16 + lhi * 4 + j;   // local row 0..63
        comb[wc][lr][0] = p0; comb[wc][lr][1] = p1; comb[wc][lr][2] = p2;
        comb[wc][lr][3] = p3; comb[wc][lr][4] = p4;
        comb[wc][lr][5] = p5; comb[wc][lr][6] = p6;
      }
    }
  }
  __syncthreads();
  if (t < BM) {
    const int row = bm + t;
#pragma unroll
    for (int q = 0; q < 7; ++q)
      Hpart[(size_t)(xblk * 7 + q) * MROWS + row] =
          comb[0][t][q] + comb[1][t][q];
  }
#undef STAGE
#undef COMPUTE
#undef STEP
}

// ---------------------------------------------------------------------------
// Kernel 3: finalize + contact. Folds the 4 Hpart slices (contiguous float4
// plane reads for cj). Contact stores are nontemporal via ext-vector f32x4
// (the builtin rejects HIP's float4 class type — R16 compile fix).
// ---------------------------------------------------------------------------
__global__ __launch_bounds__(256) void k_fc(const float* __restrict__ Hpart,
                                            const float* __restrict__ bss,
                                            const float* __restrict__ bang,
                                            const float* __restrict__ bc,
                                            float* __restrict__ ssO,
                                            float* __restrict__ angO,
                                            float* __restrict__ contact) {
  __shared__ float cj_l[LSEQ];
  __shared__ float ci_l[ITILE];
  const int blk = blockIdx.x;
  const int b   = blk >> 8;
  const int i0  = (blk & 255) * ITILE;
  const int t   = threadIdx.x;
  const size_t rowbase = (size_t)b * LSEQ;

  {
    const float* p0 = Hpart + (size_t)(0 * 7 + 6) * MROWS + rowbase;
    const float* p1 = Hpart + (size_t)(1 * 7 + 6) * MROWS + rowbase;
    const float* p2 = Hpart + (size_t)(2 * 7 + 6) * MROWS + rowbase;
    const float* p3 = Hpart + (size_t)(3 * 7 + 6) * MROWS + rowbase;
#pragma unroll
    for (int it = 0; it < 2; ++it) {
      const int j = it * 1024 + t * 4;
      const float4 a = *(const float4*)&p0[j];
      const float4 bq = *(const float4*)&p1[j];
      const float4 c = *(const float4*)&p2[j];
      const float4 d = *(const float4*)&p3[j];
      float4 s;
      s.x = a.x + bq.x + c.x + d.x;
      s.y = a.y + bq.y + c.y + d.y;
      s.z = a.z + bq.z + c.z + d.z;
      s.w = a.w + bq.w + c.w + d.w;
      *(float4*)&cj_l[j] = s;
    }
  }
  if (t < ITILE) {
    const size_t r = rowbase + i0 + t;
    float q[6] = {0, 0, 0, 0, 0, 0};
#pragma unroll
    for (int s = 0; s < 4; ++s)
#pragma unroll
      for (int qq = 0; qq < 6; ++qq)
        q[qq] += Hpart[(size_t)(s * 7 + qq) * MROWS + r];
    const float l0 = q[0] + bss[0], l1 = q[1] + bss[1], l2 = q[2] + bss[2];
    const float mx = fmaxf(l0, fmaxf(l1, l2));
    const float e0 = __expf(l0 - mx), e1 = __expf(l1 - mx), e2 = __expf(l2 - mx);
    const float inv = 1.f / (e0 + e1 + e2);
    ssO[r * 3 + 0] = e0 * inv;
    ssO[r * 3 + 1] = e1 * inv;
    ssO[r * 3 + 2] = e2 * inv;
    angO[r * 2 + 0] = q[3] + bang[0];
    angO[r * 2 + 1] = q[4] + bang[1];
    ci_l[t] = q[5] + bc[0];
  }
  __syncthreads();

#pragma unroll
  for (int r = 0; r < ITILE; ++r) {
    const float base = ci_l[r];
    float* orow = contact + (rowbase + i0 + r) * LSEQ;
#pragma unroll
    for (int jc = 0; jc < 2; ++jc) {
      const int j0 = jc * 1024 + t * 4;
      const float4 c4 = *(const float4*)&cj_l[j0];
      f32x4 o;
      o[0] = 1.f / (1.f + __expf(-(base + c4.x)));
      o[1] = 1.f / (1.f + __expf(-(base + c4.y)));
      o[2] = 1.f / (1.f + __expf(-(base + c4.z)));
      o[3] = 1.f / (1.f + __expf(-(base + c4.w)));
      __builtin_nontemporal_store(o, (f32x4*)&orow[j0]);
    }
  }
}

// ---------------------------------------------------------------------------
extern "C" void kernel_launch(void* const* d_in, const int* in_sizes, int n_in,
                              void* d_out, int out_size, void* d_ws, size_t ws_size,
                              hipStream_t stream) {
  const float* X    = (const float*)d_in[0];
  const float* W1   = (const float*)d_in[1];
  const float* b1   = (const float*)d_in[2];
  const float* W2   = (const float*)d_in[3];
  const float* b2   = (const float*)d_in[4];
  const float* Wss  = (const float*)d_in[5];
  const float* bss  = (const float*)d_in[6];
  const float* Wang = (const float*)d_in[7];
  const float* bang = (const float*)d_in[8];
  const float* Wc   = (const float*)d_in[9];
  const float* bc   = (const float*)d_in[10];

  float* out     = (float*)d_out;
  float* ssO     = out;                         // [8192,3]
  float* angO    = out + 24576;                 // [8192,2]
  float* contact = out + 40960;                 // [4,2048,2048]

  // h1/W2t scratch inside the not-yet-written contact region (k_fc reads
  // only ws + biases and overwrites the region last).
  ushort* h1  = (ushort*)contact;                        // 8 MB  (swizzled)
  ushort* W2t = (ushort*)(contact + 2 * 1024 * 1024);    // 512 KB (swizzled)

  // ws: Hpart[4][7][8192] f32 = 896 KB (read by k_fc while contact is being
  // written, so it must NOT alias the contact region).
  float* Hpart = (float*)d_ws;

  k_prep<<<768, 256, 0, stream>>>(X, W1, b1, W2, h1, W2t);
  k_gemm_heads<<<512, 256, 0, stream>>>(h1, W2t, b2, Wss, Wang, Wc, Hpart);
  k_fc<<<1024, 256, 0, stream>>>(Hpart, bss, bang, bc, ssO, angO, contact);
}